// Round 1
// 384.400 us; speedup vs baseline: 1.0551x; 1.0551x over previous
//
#include <hip/hip_runtime.h>
#include <hip/hip_bf16.h>

// Problem constants
#define B_   8
#define LQ   1024
#define LK   8192
#define D_   256
#define DC   128
#define EPSF 1e-6f

typedef __attribute__((ext_vector_type(8))) short short8;   // 8 bf16 (4 VGPRs)
typedef __attribute__((ext_vector_type(4))) float floatx4;  // 4 fp32 acc

static __device__ __forceinline__ floatx4 mfma16(short8 a, short8 b, floatx4 c) {
    return __builtin_amdgcn_mfma_f32_16x16x32_bf16(a, b, c, 0, 0, 0);
}
static __device__ __forceinline__ float fast_rcp(float x)  { return __builtin_amdgcn_rcpf(x); }
static __device__ __forceinline__ float fast_sqrt(float x) { return __builtin_amdgcn_sqrtf(x); }
static __device__ __forceinline__ float fast_ln(float x)   { return 0.69314718056f * __builtin_amdgcn_logf(x); }

// ---------------------------------------------------------------------------
// K1: G = W_up^T @ W_up  (128x128), stored bf16 row-major. 256 threads/block:
// two half-depth partials (h=0: d<128, h=1: d>=128) combined through LDS —
// halves the dependent-load chain of the old 128-thread version.
__global__ __launch_bounds__(256) void k_G(const float* __restrict__ W,
                                           __hip_bfloat16* __restrict__ G) {
    __shared__ float red[128];
    int c1 = blockIdx.x;
    int t = threadIdx.x, c2 = t & 127, h = t >> 7;
    int d0 = h * 128;
    float a0 = 0.f, a1 = 0.f, a2 = 0.f, a3 = 0.f;
#pragma unroll 4
    for (int d = 0; d < 128; d += 4) {
        a0 += W[(size_t)(d0 + d + 0) * DC + c1] * W[(size_t)(d0 + d + 0) * DC + c2];
        a1 += W[(size_t)(d0 + d + 1) * DC + c1] * W[(size_t)(d0 + d + 1) * DC + c2];
        a2 += W[(size_t)(d0 + d + 2) * DC + c1] * W[(size_t)(d0 + d + 2) * DC + c2];
        a3 += W[(size_t)(d0 + d + 3) * DC + c1] * W[(size_t)(d0 + d + 3) * DC + c2];
    }
    float s = (a0 + a1) + (a2 + a3);
    if (h) red[c2] = s;
    __syncthreads();
    if (!h) G[c1 * DC + c2] = __float2bfloat16(s + red[c2]);
}

// ---------------------------------------------------------------------------
// K2: q_proj = (q @ W_up) -> bf16 (8192 x 128), with q_sq fused into the
// staging pass (q is already in registers there — saves a full 8 MB re-read
// and one kernel launch vs the old separate k_qsq).
__global__ __launch_bounds__(256) void k_qproj(const float* __restrict__ q,
                                               const float* __restrict__ W,
                                               __hip_bfloat16* __restrict__ qproj,
                                               float* __restrict__ q_sq) {
    __shared__ __hip_bfloat16 sA[64 * 72];   // q chunk (64 rows x 64 cols)
    __shared__ __hip_bfloat16 sB[128 * 72];  // W^T chunk: row=c, col=d_local
    int t = threadIdx.x, lane = t & 63, w = t >> 6;
    int quad = lane >> 4, li = lane & 15;
    int row0 = blockIdx.x * 64;

    float psum[4] = {0.f, 0.f, 0.f, 0.f};    // partial q_sq, row = it*16 + (t>>4)
    floatx4 acc[8];
#pragma unroll
    for (int nt = 0; nt < 8; ++nt) acc[nt] = (floatx4){0.f, 0.f, 0.f, 0.f};

    for (int kc4 = 0; kc4 < 4; ++kc4) {
        // stage q chunk (fp32 -> bf16): 64 rows x 64 cols = 1024 float4
#pragma unroll
        for (int it = 0; it < 4; ++it) {
            int idx = it * 256 + t;
            int r = idx >> 4, pos = idx & 15;
            float4 v = *(const float4*)(q + (size_t)(row0 + r) * D_ + kc4 * 64 + pos * 4);
            psum[it] += v.x * v.x + v.y * v.y + v.z * v.z + v.w * v.w;
            __hip_bfloat16* dst = &sA[r * 72 + pos * 4];
            dst[0] = __float2bfloat16(v.x); dst[1] = __float2bfloat16(v.y);
            dst[2] = __float2bfloat16(v.z); dst[3] = __float2bfloat16(v.w);
        }
        // stage W^T chunk: sB[c*72 + dl] = W[(kc4*64+dl)*128 + c]
#pragma unroll
        for (int it = 0; it < 32; ++it) {
            int e = it * 256 + t;
            int dl = e >> 7, c = e & 127;
            sB[c * 72 + dl] = __float2bfloat16(W[(size_t)(kc4 * 64 + dl) * DC + c]);
        }
        __syncthreads();
        short8 af[2];
#pragma unroll
        for (int ks = 0; ks < 2; ++ks)
            af[ks] = *(const short8*)&sA[(w * 16 + li) * 72 + ks * 32 + quad * 8];
#pragma unroll
        for (int nt = 0; nt < 8; ++nt)
#pragma unroll
            for (int ks = 0; ks < 2; ++ks) {
                short8 bf = *(const short8*)&sB[(nt * 16 + li) * 72 + ks * 32 + quad * 8];
                acc[nt] = mfma16(af[ks], bf, acc[nt]);
            }
        __syncthreads();
    }
#pragma unroll
    for (int nt = 0; nt < 8; ++nt)
#pragma unroll
        for (int r = 0; r < 4; ++r) {
            int row = w * 16 + quad * 4 + r;
            qproj[(size_t)(row0 + row) * DC + nt * 16 + li] = __float2bfloat16(acc[nt][r]);
        }
    // q_sq: threads sharing (t>>4) are the 16 lanes of one quad -> shfl tree
#pragma unroll
    for (int it = 0; it < 4; ++it) {
        float s = psum[it];
        s += __shfl_xor(s, 1); s += __shfl_xor(s, 2);
        s += __shfl_xor(s, 4); s += __shfl_xor(s, 8);
        if (li == 0) q_sq[row0 + it * 16 + w * 4 + quad] = s;
    }
}

// ---------------------------------------------------------------------------
// K3 (fused dequant + k_sq): dequantize 128 rows of codes -> bf16 (to global
// kc AND LDS), then k_sq[l] = kc[l,:] @ G @ kc[l,:]^T via MFMA + row-dot.
// G read straight from L1/L2 (32 KB, shared by all blocks). sK padded to 132.
__global__ __launch_bounds__(256) void k_dq_ksq(const int* __restrict__ kq,
                                                const float* __restrict__ kscale,
                                                const float* __restrict__ kzero,
                                                const __hip_bfloat16* __restrict__ G,
                                                __hip_bfloat16* __restrict__ kc,
                                                float* __restrict__ k_sq) {
    __shared__ __hip_bfloat16 sK[128 * 132];   // 33.8 KB
    int t = threadIdx.x, lane = t & 63, w = t >> 6;
    int quad = lane >> 4, li = lane & 15;
    int b = blockIdx.x >> 6, l0 = (blockIdx.x & 63) * 128;

    // dequant: 4096 int4-groups; col constant per thread across iterations
    const int4* codes = (const int4*)(kq + ((size_t)b * LK + l0) * DC);
    int col = (t & 31) * 4;
    float4 sc = *(const float4*)(kscale + b * DC + col);
    float4 zp = *(const float4*)(kzero + b * DC + col);
    __hip_bfloat16* kco = kc + ((size_t)b * LK + l0) * DC;
#pragma unroll
    for (int it = 0; it < 16; ++it) {
        int idx = it * 256 + t;            // [0,4096)
        int r = idx >> 5;
        int4 c4 = codes[idx];
        __hip_bfloat16 tmp[4];
        tmp[0] = __float2bfloat16(sc.x * ((float)c4.x - zp.x));
        tmp[1] = __float2bfloat16(sc.y * ((float)c4.y - zp.y));
        tmp[2] = __float2bfloat16(sc.z * ((float)c4.z - zp.z));
        tmp[3] = __float2bfloat16(sc.w * ((float)c4.w - zp.w));
        *(uint2*)&sK[r * 132 + col] = *(const uint2*)tmp;
        *(uint2*)(kco + idx * 4)    = *(const uint2*)tmp;
    }
    __syncthreads();

    short8 af[2][4];
#pragma unroll
    for (int mt = 0; mt < 2; ++mt)
#pragma unroll
        for (int ks = 0; ks < 4; ++ks)
            af[mt][ks] = *(const short8*)&sK[(w * 32 + mt * 16 + li) * 132 + ks * 32 + quad * 8];
    float s[2][4] = {{0, 0, 0, 0}, {0, 0, 0, 0}};
#pragma unroll
    for (int nt = 0; nt < 8; ++nt) {
        floatx4 a0 = (floatx4){0.f, 0.f, 0.f, 0.f};
        floatx4 a1 = (floatx4){0.f, 0.f, 0.f, 0.f};
#pragma unroll
        for (int ks = 0; ks < 4; ++ks) {
            // B[k=c1][n=c2] = G[c2][c1] (G symmetric) — contiguous along c1
            short8 bf = *(const short8*)(G + (size_t)(nt * 16 + li) * DC + ks * 32 + quad * 8);
            a0 = mfma16(af[0][ks], bf, a0);
            a1 = mfma16(af[1][ks], bf, a1);
        }
        int c2 = nt * 16 + li;
#pragma unroll
        for (int r = 0; r < 4; ++r) {
            int r0 = w * 32 +      quad * 4 + r;
            int r1 = w * 32 + 16 + quad * 4 + r;
            s[0][r] += a0[r] * __bfloat162float(sK[r0 * 132 + c2]);
            s[1][r] += a1[r] * __bfloat162float(sK[r1 * 132 + c2]);
        }
    }
#pragma unroll
    for (int mt = 0; mt < 2; ++mt)
#pragma unroll
        for (int r = 0; r < 4; ++r) {
            float v = s[mt][r];
            v += __shfl_xor(v, 1); v += __shfl_xor(v, 2);
            v += __shfl_xor(v, 4); v += __shfl_xor(v, 8);
            if (li == 0)
                k_sq[(size_t)b * LK + l0 + w * 32 + mt * 16 + quad * 4 + r] = v;
        }
}

// ---------------------------------------------------------------------------
// K4: main — qk = q_proj @ k_c^T (128x128 tile, K=128 in 2 pipelined halves).
// OPERAND-SWAPPED MFMA: A=kc frag, B=qproj frag -> D[row=n-local, col=m].
// Each thread's acc quad = 4 CONSECUTIVE n columns => float4 nontemporal
// stores (16 dwordx4/thread instead of 64 scalar dwords). LDS reads unchanged
// (A/B fragment addressing is symmetric: both are [row|col][k] short8 reads).
__global__ __launch_bounds__(256) void k_main(const __hip_bfloat16* __restrict__ qproj,
                                              const __hip_bfloat16* __restrict__ kc,
                                              const float* __restrict__ q_sq,
                                              const float* __restrict__ k_sq,
                                              float* __restrict__ out) {
    __shared__ __hip_bfloat16 sA[128 * 72];
    __shared__ __hip_bfloat16 sB[128 * 72];
    int t = threadIdx.x, lane = t & 63, w = t >> 6;
    int quad = lane >> 4, li = lane & 15;
    int wm = w >> 1, wn = w & 1;
    int n0 = blockIdx.x * 128, m0 = blockIdx.y * 128, b = blockIdx.z;
    const uint4* Ag = (const uint4*)(qproj + ((size_t)b * LQ + m0) * DC);  // 16 u4/row
    const uint4* Bg = (const uint4*)(kc   + ((size_t)b * LK + n0) * DC);
    uint4* dA = (uint4*)sA; uint4* dB = (uint4*)sB;

    floatx4 acc[4][4];   // [i: m-frag][j: n-frag]; reg r = n-local (quad*4+r)
#pragma unroll
    for (int i = 0; i < 4; ++i)
#pragma unroll
        for (int j = 0; j < 4; ++j)
            acc[i][j] = (floatx4){0.f, 0.f, 0.f, 0.f};

    int r_ = t >> 3, ch_ = t & 7;          // 32 rows x 8 chunks per 256-thread pass
    // ---- load half 0 ----
    uint4 ra[4], rb[4];
#pragma unroll
    for (int it = 0; it < 4; ++it) {
        ra[it] = Ag[(it * 32 + r_) * 16 + ch_];
        rb[it] = Bg[(it * 32 + r_) * 16 + ch_];
    }
#pragma unroll
    for (int it = 0; it < 4; ++it) {
        dA[(it * 32 + r_) * 9 + ch_] = ra[it];
        dB[(it * 32 + r_) * 9 + ch_] = rb[it];
    }
    __syncthreads();
    // ---- prefetch half 1 while computing half 0 ----
#pragma unroll
    for (int it = 0; it < 4; ++it) {
        ra[it] = Ag[(it * 32 + r_) * 16 + 8 + ch_];
        rb[it] = Bg[(it * 32 + r_) * 16 + 8 + ch_];
    }
#pragma unroll
    for (int ks = 0; ks < 2; ++ks) {
        short8 qf[4], kf[4];
#pragma unroll
        for (int i = 0; i < 4; ++i) {
            qf[i] = *(const short8*)&sA[(wm * 64 + i * 16 + li) * 72 + ks * 32 + quad * 8];
            kf[i] = *(const short8*)&sB[(wn * 64 + i * 16 + li) * 72 + ks * 32 + quad * 8];
        }
#pragma unroll
        for (int i = 0; i < 4; ++i)
#pragma unroll
            for (int j = 0; j < 4; ++j)
                acc[i][j] = mfma16(kf[j], qf[i], acc[i][j]);   // A=kc, B=qproj
    }
    __syncthreads();
#pragma unroll
    for (int it = 0; it < 4; ++it) {
        dA[(it * 32 + r_) * 9 + ch_] = ra[it];
        dB[(it * 32 + r_) * 9 + ch_] = rb[it];
    }
    __syncthreads();
#pragma unroll
    for (int ks = 0; ks < 2; ++ks) {
        short8 qf[4], kf[4];
#pragma unroll
        for (int i = 0; i < 4; ++i) {
            qf[i] = *(const short8*)&sA[(wm * 64 + i * 16 + li) * 72 + ks * 32 + quad * 8];
            kf[i] = *(const short8*)&sB[(wn * 64 + i * 16 + li) * 72 + ks * 32 + quad * 8];
        }
#pragma unroll
        for (int i = 0; i < 4; ++i)
#pragma unroll
            for (int j = 0; j < 4; ++j)
                acc[i][j] = mfma16(kf[j], qf[i], acc[i][j]);
    }

    // epilogue: dist = arccosh(1 + 2*diff/denom). k_sq now loads as float4
    // (n-contiguous per thread); output stored as nontemporal float4.
    floatx4 ks4[4], kn4[4];
#pragma unroll
    for (int j = 0; j < 4; ++j) {
        ks4[j] = *(const floatx4*)(k_sq + (size_t)b * LK + n0 + wn * 64 + j * 16 + quad * 4);
#pragma unroll
        for (int r = 0; r < 4; ++r)
            kn4[j][r] = 1.f - fminf(ks4[j][r], 1.f - EPSF);
    }
#pragma unroll
    for (int i = 0; i < 4; ++i) {
        int m = m0 + wm * 64 + i * 16 + li;
        float qs  = q_sq[(size_t)b * LQ + m];
        float omq = 1.f - fminf(qs, 1.f - EPSF);
        float* orow = out + ((size_t)b * LQ + m) * (size_t)LK + n0 + wn * 64;
#pragma unroll
        for (int j = 0; j < 4; ++j) {
            floatx4 o;
#pragma unroll
            for (int r = 0; r < 4; ++r) {
                float diff  = fmaxf(qs + ks4[j][r] - 2.f * acc[i][j][r], 0.f);
                float delta = 2.f * diff * fast_rcp(omq * kn4[j][r] + EPSF);
                float sq    = fast_sqrt(delta * (delta + 2.f));
                o[r] = fast_ln(1.f + delta + sq);
            }
            __builtin_nontemporal_store(o, (floatx4*)(orow + j * 16 + quad * 4));
        }
    }
}

// ---------------------------------------------------------------------------
extern "C" void kernel_launch(void* const* d_in, const int* in_sizes, int n_in,
                              void* d_out, int out_size, void* d_ws, size_t ws_size,
                              hipStream_t stream) {
    const float* q      = (const float*)d_in[0];
    const int*   kq     = (const int*)d_in[1];
    const float* kscale = (const float*)d_in[2];
    const float* kzero  = (const float*)d_in[3];
    const float* W      = (const float*)d_in[4];
    float* out = (float*)d_out;

    // workspace layout (19.2 MB total)
    char* ws = (char*)d_ws;
    __hip_bfloat16* qproj = (__hip_bfloat16*)(ws);                 // 2,097,152 B
    __hip_bfloat16* kc    = (__hip_bfloat16*)(ws + 2097152);       // 16,777,216 B
    __hip_bfloat16* G     = (__hip_bfloat16*)(ws + 18874368);      //    32,768 B
    float*          q_sq  = (float*)(ws + 18907136);               //    32,768 B
    float*          k_sq  = (float*)(ws + 18939904);               //   262,144 B

    k_G     <<<128, 256, 0, stream>>>(W, G);
    k_qproj <<<128, 256, 0, stream>>>(q, W, qproj, q_sq);
    k_dq_ksq<<<512, 256, 0, stream>>>(kq, kscale, kzero, G, kc, k_sq);
    dim3 grid(LK / 128, LQ / 128, B_);
    k_main  <<<grid, 256, 0, stream>>>(qproj, kc, q_sq, k_sq, out);
}